// Round 14
// baseline (908.532 us; speedup 1.0000x reference)
//
#include <hip/hip_runtime.h>
#include <cstdint>
#include <cstddef>

#define T_STEPS 24
#define BATCH 8
#define CHN 16
#define HH 96
#define WW 96
#define HW (HH*WW)            // 9216
#define NPIX (BATCH*HW)       // 73728
#define NELEM (BATCH*CHN*HW)  // 1179648
#define NBLK 1152             // 64 px per block

typedef float f32x2 __attribute__((ext_vector_type(2)));

// Threefry-2x32, 20 rounds — matches jax._src.prng lowering exactly.
__host__ __device__ inline void tf2x32(uint32_t k0, uint32_t k1,
                                       uint32_t x0, uint32_t x1,
                                       uint32_t& o0, uint32_t& o1) {
  const uint32_t ks2 = k0 ^ k1 ^ 0x1BD11BDAu;
  uint32_t v0 = x0 + k0, v1 = x1 + k1;
#define RR(d) { v0 += v1; v1 = (v1 << (d)) | (v1 >> (32 - (d))); v1 ^= v0; }
  RR(13) RR(15) RR(26) RR(6)
  v0 += k1;  v1 += ks2 + 1u;
  RR(17) RR(29) RR(16) RR(24)
  v0 += ks2; v1 += k0 + 2u;
  RR(13) RR(15) RR(26) RR(6)
  v0 += k0;  v1 += k1 + 3u;
  RR(17) RR(29) RR(16) RR(24)
  v0 += k1;  v1 += ks2 + 4u;
  RR(13) RR(15) RR(26) RR(6)
  v0 += ks2; v1 += k0 + 5u;
#undef RR
  o0 = v0; o1 = v1;
}

// One-time: w2 (128h,48k) -> w2t (48k,128h); w3 (16,128) -> w3t (128,16).
__global__ __launch_bounds__(256) void wt_transpose(
    const float* __restrict__ w2, const float* __restrict__ w3,
    float* __restrict__ w2t, float* __restrict__ w3t)
{
  const int idx = blockIdx.x * 256 + threadIdx.x;   // [0, 8192)
  if (idx < 6144) {
    const int k = idx >> 7, h = idx & 127;
    w2t[idx] = w2[h * 48 + k];
  } else {
    const int i = idx - 6144;                       // [0, 2048)
    const int o = i >> 4, cc = i & 15;
    w3t[i] = w3[cc * 128 + o];
  }
}

// MODE: 0 = first step (no mask), 1 = full step, 2 = CONV_ONLY diagnostic
// (mask+conv+threefry+y-store+barrier+keepalive write; GEMMs skipped),
// 3 = EMPTY diagnostic (addr calc + 1B store: pure dispatch overhead).
// Diagnostics write ONLY dead buffers; real output unchanged.
template <int MODE>
__global__ __launch_bounds__(256, 5) void nca_step(
    const float* __restrict__ xin,
    float* __restrict__ frames_prev,
    const uint8_t* __restrict__ alive_prev,
    float* __restrict__ xnew,
    uint8_t* __restrict__ alive_cur,
    const float* __restrict__ w2t, const float* __restrict__ w3t,
    uint32_t k0, uint32_t k1)
{
  __shared__ float smem[4096];                     // 16384 B
  float* y_t = smem;                               // [48][66]   conv .. GEMM1
  float (*part)[4][64] = (float (*)[4][64])smem;   // [16][4][64] after B2

  const int tid  = threadIdx.x;
  const int lane = tid & 63;
  const int sub  = __builtin_amdgcn_readfirstlane(tid >> 6); // 0..3
  const int bid  = blockIdx.x;
  const int vbid = (bid & 7) * 144 + (bid >> 3);   // XCD-bijective swizzle
  const int P    = vbid * 64;

  if constexpr (MODE == 3) {                       // EMPTY: pure overhead
    alive_cur[P + lane] = 1;
    return;
  }

  const int b    = P / HW;
  const int p0   = P - b * HW;
  const int p    = p0 + lane;
  const int r    = p / WW;
  const int c    = p - r * WW;
  const bool rn = r > 0, rs = r < HH - 1, cw = c > 0, ce = c < WW - 1;
  constexpr bool MASK = (MODE >= 1);

  // ---- Mask-on-read: f at the 9 neighbor positions of p ----
  float f[9];
  #pragma unroll
  for (int i = 0; i < 9; ++i) f[i] = 1.f;
  if constexpr (MASK) {
    const float* x3 = xin + ((size_t)(b * CHN + 3)) * HW + p;
    const uint8_t* ap = alive_prev + (size_t)b * HW + p;
    const bool rvs[5] = { r > 1, rn, true, rs, r < HH - 2 };
    const bool cvs[5] = { c > 1, cw, true, ce, c < WW - 2 };
    float hm[5][3];                       // horizontal max3, rows r-2..r+2
    #pragma unroll
    for (int i = 0; i < 5; ++i) {
      const int off = (i - 2) * WW;
      const bool rv = rvs[i];
      const float a0 = (rv && cvs[0]) ? x3[off - 2] : 0.f;
      const float a1 = (rv && cvs[1]) ? x3[off - 1] : 0.f;
      const float a2 =  rv            ? x3[off]     : 0.f;
      const float a3 = (rv && cvs[3]) ? x3[off + 1] : 0.f;
      const float a4 = (rv && cvs[4]) ? x3[off + 2] : 0.f;
      hm[i][0] = fmaxf(fmaxf(a0, a1), a2);
      hm[i][1] = fmaxf(fmaxf(a1, a2), a3);
      hm[i][2] = fmaxf(fmaxf(a2, a3), a4);
    }
    #pragma unroll
    for (int qr = 0; qr < 3; ++qr)
      #pragma unroll
      for (int qc = 0; qc < 3; ++qc) {
        const float mp = fmaxf(fmaxf(hm[qr][qc], hm[qr + 1][qc]),
                               hm[qr + 2][qc]);
        const bool inb = rvs[qr + 1] && cvs[qc + 1];
        const uint8_t al = inb ? ap[(qr - 1) * WW + (qc - 1)] : (uint8_t)0;
        f[qr * 3 + qc] = (inb && al && (mp > 0.1f)) ? 1.f : 0.f;
      }
  }

  // ---- Conv on masked values: wave `sub` does channels 4*sub..4*sub+3 ----
  float n11m[4];
  #pragma unroll
  for (int cq = 0; cq < 4; ++cq) {
    const int ch = sub * 4 + cq;
    const size_t jb = ((size_t)(b * CHN + ch)) * HW + p;
    const float* xc = xin + jb;
    float n00 = (rn && cw) ? xc[-WW - 1] : 0.f;
    float n01 = rn         ? xc[-WW]     : 0.f;
    float n02 = (rn && ce) ? xc[-WW + 1] : 0.f;
    float n10 = cw         ? xc[-1]      : 0.f;
    float n11 =              xc[0];
    float n12 = ce         ? xc[1]       : 0.f;
    float n20 = (rs && cw) ? xc[WW - 1]  : 0.f;
    float n21 = rs         ? xc[WW]      : 0.f;
    float n22 = (rs && ce) ? xc[WW + 1]  : 0.f;
    if constexpr (MASK) {
      n00 *= f[0]; n01 *= f[1]; n02 *= f[2];
      n10 *= f[3]; n11 *= f[4]; n12 *= f[5];
      n20 *= f[6]; n21 *= f[7]; n22 *= f[8];
      frames_prev[jb] = n11;               // scratch for MODE==2
    }
    n11m[cq] = n11;
    y_t[(3 * ch + 0) * 66 + lane] = n11;
    y_t[(3 * ch + 1) * 66 + lane] =
        ((n02 + n22 - n00 - n20) + 2.f * (n12 - n10)) * 0.125f;
    y_t[(3 * ch + 2) * 66 + lane] =
        ((n20 + n22 - n00 - n02) + 2.f * (n21 - n01)) * 0.125f;
    if (ch == 3) {
      float m = fmaxf(fmaxf(fmaxf(n00, n01), fmaxf(n02, n10)),
                      fmaxf(fmaxf(n11, n12), fmaxf(n20, n21)));
      m = fmaxf(m, n22);
      alive_cur[P + lane] = (m > 0.1f) ? 1 : 0;
    }
  }

  // ---- Threefry ----
  float keep[4];
  #pragma unroll
  for (int i = 0; i < 4; ++i) {
    const int cc = sub * 4 + i;
    const uint32_t j = (uint32_t)((b * CHN + cc) * HW + p);
    uint32_t o0, o1;
    tf2x32(k0, k1, 0u, j, o0, o1);
    const uint32_t bits = o0 ^ o1;
    keep[i] = ((bits >> 9) > 0x400000u) ? 1.f : 0.f;
  }

  __syncthreads();   // B0: y ready

  if constexpr (MODE == 2) {
    // CONV_ONLY keep-alive: consume y/keep/n11m via stores, skip GEMMs.
    #pragma unroll
    for (int i = 0; i < 4; ++i) {
      const int cc = sub * 4 + i;
      const uint32_t j = (uint32_t)((b * CHN + cc) * HW + p);
      xnew[j] = n11m[i] + keep[i] * y_t[(3 * cc + 1) * 66 + lane];
    }
    return;
  }

  // ---- GEMM1: lane = px; acc[j] = h pair {sub*32+2j, sub*32+2j+1}[px] ----
  f32x2 acc[16];
  #pragma unroll
  for (int j = 0; j < 16; ++j) acc[j] = (f32x2){0.f, 0.f};

  const f32x2* w2b2 = (const f32x2*)(w2t + sub * 32);
  #pragma unroll
  for (int k = 0; k < 48; ++k) {
    const float yvk = y_t[k * 66 + lane];
    const f32x2 yv2 = {yvk, yvk};
    const f32x2* w2r = w2b2 + k * 64;               // wave-uniform address
    #pragma unroll
    for (int j = 0; j < 16; ++j)
      acc[j] = __builtin_elementwise_fma(w2r[j], yv2, acc[j]);
  }

  // ---- GEMM2 ----
  f32x2 o2[8];
  #pragma unroll
  for (int i = 0; i < 8; ++i) o2[i] = (f32x2){0.f, 0.f};

  const f32x2* w3b2 = (const f32x2*)(w3t + (size_t)sub * 32 * 16);
  #pragma unroll
  for (int hh = 0; hh < 32; ++hh) {
    const float av = (hh & 1) ? acc[hh >> 1].y : acc[hh >> 1].x;
    const float hv = fmaxf(av, 0.f);
    const f32x2 hv2 = {hv, hv};
    const f32x2* w3r = w3b2 + hh * 8;               // wave-uniform
    #pragma unroll
    for (int n = 0; n < 8; ++n)
      o2[n] = __builtin_elementwise_fma(w3r[n], hv2, o2[n]);
  }

  __syncthreads();   // B2

  #pragma unroll
  for (int cc = 0; cc < CHN; ++cc)
    part[cc][sub][lane] = (cc & 1) ? o2[cc >> 1].y : o2[cc >> 1].x;
  __syncthreads();   // B3

  #pragma unroll
  for (int i = 0; i < 4; ++i) {
    const int cc = sub * 4 + i;
    const float s = (part[cc][0][lane] + part[cc][1][lane]) +
                    (part[cc][2][lane] + part[cc][3][lane]);
    const uint32_t j = (uint32_t)((b * CHN + cc) * HW + p);
    xnew[j] = n11m[i] + keep[i] * s;
  }
}

// Final mask pass (only for frames[23]): thread per (pixel, channel-quad).
__global__ __launch_bounds__(256) void nca_mask(
    const float* __restrict__ xnew, const uint8_t* __restrict__ alive_pre,
    float* __restrict__ xout)
{
  const int lane = threadIdx.x & 63;
  const int quad = threadIdx.x >> 6;
  const int bid  = blockIdx.x;
  const int vbid = (bid & 7) * 144 + (bid >> 3);
  const int pix  = vbid * 64 + lane;
  const int b = pix / HW;
  const int p = pix - b * HW;
  const int r = p / WW;
  const int c = p - r * WW;
  const bool rn = r > 0, rs = r < HH - 1, cw = c > 0, ce = c < WW - 1;

  const float* x3 = xnew + ((size_t)b * CHN + 3) * HW + p;
  float m = x3[0];
  if (rn) {
    m = fmaxf(m, x3[-WW]);
    if (cw) m = fmaxf(m, x3[-WW - 1]);
    if (ce) m = fmaxf(m, x3[-WW + 1]);
  }
  if (cw) m = fmaxf(m, x3[-1]);
  if (ce) m = fmaxf(m, x3[1]);
  if (rs) {
    m = fmaxf(m, x3[WW]);
    if (cw) m = fmaxf(m, x3[WW - 1]);
    if (ce) m = fmaxf(m, x3[WW + 1]);
  }
  const float f = ((m > 0.1f) && alive_pre[pix]) ? 1.f : 0.f;

  const size_t base = ((size_t)b * CHN + quad * 4) * HW + p;
  #pragma unroll
  for (int i = 0; i < 4; ++i)
    xout[base + (size_t)i * HW] = xnew[base + (size_t)i * HW] * f;
}

extern "C" void kernel_launch(void* const* d_in, const int* in_sizes, int n_in,
                              void* d_out, int out_size, void* d_ws, size_t ws_size,
                              hipStream_t stream) {
  const float* x0 = (const float*)d_in[0];
  const float* w2 = (const float*)d_in[3];  // (128,48)
  const float* w3 = (const float*)d_in[4];  // (16,128)
  float* out = (float*)d_out;               // (24,8,16,96,96)

  char* ws = (char*)d_ws;
  float*   xlast  = (float*)ws;                                  // NELEM f32
  uint8_t* aliveA = (uint8_t*)(ws + (size_t)NELEM * 4);          // NPIX B
  uint8_t* aliveB = aliveA + NPIX;                               // NPIX B
  float*   w3t    = (float*)(ws + (size_t)NELEM * 4 + 2 * (size_t)NPIX);
  float*   w2t    = w3t + 2048;                                  // 6144 f32

  uint32_t keys[T_STEPS][2];
  for (int t = 0; t < T_STEPS; ++t) {
    uint32_t a, b;
    tf2x32(0u, 42u, 0u, (uint32_t)t, a, b);
    keys[t][0] = a; keys[t][1] = b;
  }

  wt_transpose<<<32, 256, 0, stream>>>(w2, w3, w2t, w3t);

  // ---- Real pipeline (identical to 662-µs best) ----
  nca_step<0><<<NBLK, 256, 0, stream>>>(
      x0, nullptr, nullptr, out + (size_t)1 * NELEM, aliveA, w2t, w3t,
      keys[0][0], keys[0][1]);

  for (int t = 1; t < T_STEPS; ++t) {
    const float* xin  = out + (size_t)t * NELEM;
    float* frames_prv = out + (size_t)(t - 1) * NELEM;
    float* xdst = (t < T_STEPS - 1) ? out + (size_t)(t + 1) * NELEM : xlast;
    const uint8_t* aprev = (t & 1) ? aliveA : aliveB;
    uint8_t*       acur  = (t & 1) ? aliveB : aliveA;
    nca_step<1><<<NBLK, 256, 0, stream>>>(
        xin, frames_prv, aprev, xdst, acur, w2t, w3t,
        keys[t][0], keys[t][1]);
  }

  nca_mask<<<NBLK, 256, 0, stream>>>(
      xlast, (T_STEPS & 1) ? aliveA : aliveB,
      out + (size_t)(T_STEPS - 1) * NELEM);

  // ---- Diagnostics (write ONLY dead buffers: xlast, aliveA) ----
  // D1: 24x CONV_ONLY — Δ1/24 ≈ conv+mask+threefry phase + dispatch cost
  for (int d = 0; d < T_STEPS; ++d) {
    const float* xin = out + (size_t)((d % 23) + 1) * NELEM;
    nca_step<2><<<NBLK, 256, 0, stream>>>(
        xin, xlast, aliveB, xlast, aliveA, w2t, w3t,
        keys[d][0], keys[d][1]);
  }
  // D2: 24x EMPTY — Δ2/24 ≈ pure dispatch launch/ramp/drain cost
  for (int d = 0; d < T_STEPS; ++d) {
    nca_step<3><<<NBLK, 256, 0, stream>>>(
        xlast, xlast, aliveB, xlast, aliveA, w2t, w3t, 0u, 0u);
  }
}

// Round 15
// 611.076 us; speedup vs baseline: 1.4868x; 1.4868x over previous
//
#include <hip/hip_runtime.h>
#include <cstdint>
#include <cstddef>

#define T_STEPS 24
#define BATCH 8
#define CHN 16
#define HH 96
#define WW 96
#define HW (HH*WW)            // 9216
#define NPIX (BATCH*HW)       // 73728
#define NELEM (BATCH*CHN*HW)  // 1179648
#define NBLK 1152             // 64 px per block

typedef float f32x2 __attribute__((ext_vector_type(2)));
typedef float f32x4 __attribute__((ext_vector_type(4)));
typedef short bf16x8 __attribute__((ext_vector_type(8)));

// LDS plan (single 34816-B region, time-multiplexed):
//   [conv..GEMM1]  ySplit: 3 planes of [64 px][72 k] bf16 (9216 B each)
//   [post-B1]      h:      [128 h][68 px] fp32 (34816 B)
//   [post-B2]      part:   [16][4][64] fp32 (16384 B)
#define YS_ROW 144            // 72 bf16 * 2B (16B-aligned rows)
#define YS_PLANE 9216
#define H_STRIDE 68
#define SMEM_BYTES 34816

__device__ __host__ inline uint16_t bf16r(float x) {
  union { float f; uint32_t u; } v; v.f = x;
  v.u += 0x7FFFu + ((v.u >> 16) & 1u);       // RNE
  return (uint16_t)(v.u >> 16);
}
__device__ __host__ inline float bf16f(uint16_t h) {
  union { float f; uint32_t u; } v; v.u = ((uint32_t)h) << 16; return v.f;
}

// Threefry-2x32, 20 rounds — matches jax._src.prng lowering exactly.
__host__ __device__ inline void tf2x32(uint32_t k0, uint32_t k1,
                                       uint32_t x0, uint32_t x1,
                                       uint32_t& o0, uint32_t& o1) {
  const uint32_t ks2 = k0 ^ k1 ^ 0x1BD11BDAu;
  uint32_t v0 = x0 + k0, v1 = x1 + k1;
#define RR(d) { v0 += v1; v1 = (v1 << (d)) | (v1 >> (32 - (d))); v1 ^= v0; }
  RR(13) RR(15) RR(26) RR(6)
  v0 += k1;  v1 += ks2 + 1u;
  RR(17) RR(29) RR(16) RR(24)
  v0 += ks2; v1 += k0 + 2u;
  RR(13) RR(15) RR(26) RR(6)
  v0 += k0;  v1 += k1 + 3u;
  RR(17) RR(29) RR(16) RR(24)
  v0 += k1;  v1 += ks2 + 4u;
  RR(13) RR(15) RR(26) RR(6)
  v0 += ks2; v1 += k0 + 5u;
#undef RR
  o0 = v0; o1 = v1;
}

// One-time prep:
//  - w3t (128,16) transpose (unchanged GEMM2 path)
//  - wfrag: w2 (128h,48k) -> 3-term bf16 split, MFMA B-fragment order:
//    elem idx = (((s*8 + tn)*2 + kt)*64 + lane)*8 + j
//    maps to B[k][n]: n = tn*16 + (lane&15), k = kt*32 + ((lane>>4)&3)*8 + j
//    (k >= 48 zero-padded).
__global__ __launch_bounds__(256) void wt_prep(
    const float* __restrict__ w2, const float* __restrict__ w3,
    float* __restrict__ w3t, uint16_t* __restrict__ wfrag)
{
  const int idx = blockIdx.x * 256 + threadIdx.x;   // [0, 26624)
  if (idx < 24576) {
    const int j  = idx & 7;
    const int l  = (idx >> 3) & 63;
    const int kt = (idx >> 9) & 1;
    const int tn = (idx >> 10) & 7;
    const int s  = idx >> 13;                       // 0..2
    const int h  = tn * 16 + (l & 15);
    const int k  = kt * 32 + ((l >> 4) & 3) * 8 + j;
    float v = (k < 48) ? w2[h * 48 + k] : 0.f;
    const uint16_t t0 = bf16r(v);
    const float r1 = v - bf16f(t0);
    const uint16_t t1 = bf16r(r1);
    const float r2 = r1 - bf16f(t1);
    const uint16_t t2 = bf16r(r2);
    wfrag[idx] = (s == 0) ? t0 : (s == 1) ? t1 : t2;
  } else {
    const int i = idx - 24576;                      // [0, 2048)
    const int o = i >> 4, cc = i & 15;
    w3t[i] = w3[cc * 128 + o];
  }
}

// Fused step kernel. GEMM1 on matrix cores: fp32 emulated via 3-term bf16
// split (6 MFMAs of order <= 2^-16; dropped terms ~2^-23 rel = fp32-level).
// Per wave: 96 mfma_f32_16x16x32_bf16 (~500 cy) replaces 3072 cy of pk-FMA
// (R14 ablation: GEMM section = 17 us/step vs 7.7 us f32-VALU floor; fp32
// pk_fma has NO throughput gain on gfx950 so MFMA is the only lever).
// A-frag (y): row px = lane&15, k-slice (lane>>4)*8 (assumed std mapping);
// D-frag (verified m89): col h = lane&15, row px = (lane>>4)*4 + reg.
// h lands in LDS [128][68] wave-locally (wave sub owns h-cols sub*32..+32),
// GEMM2 (fp32 VALU + wave-uniform s_load w3) unchanged.
template <bool MASK>
__global__ __launch_bounds__(256, 4) void nca_step(
    const float* __restrict__ xin,
    float* __restrict__ frames_prev,
    const uint8_t* __restrict__ alive_prev,
    float* __restrict__ xnew,
    uint8_t* __restrict__ alive_cur,
    const uint16_t* __restrict__ wfrag, const float* __restrict__ w3t,
    uint32_t k0, uint32_t k1)
{
  __shared__ char smemRaw[SMEM_BYTES];
  float* h_ld = (float*)smemRaw;                       // [128][68] post-B1
  float (*part)[4][64] = (float (*)[4][64])smemRaw;    // post-B2

  const int tid  = threadIdx.x;
  const int lane = tid & 63;
  const int sub  = __builtin_amdgcn_readfirstlane(tid >> 6); // 0..3
  const int bid  = blockIdx.x;
  const int vbid = (bid & 7) * 144 + (bid >> 3);   // XCD-bijective swizzle
  const int P    = vbid * 64;
  const int b    = P / HW;
  const int p0   = P - b * HW;
  const int p    = p0 + lane;
  const int r    = p / WW;
  const int c    = p - r * WW;
  const bool rn = r > 0, rs = r < HH - 1, cw = c > 0, ce = c < WW - 1;

  // ---- Mask-on-read: f at the 9 neighbor positions of p ----
  float f[9];
  #pragma unroll
  for (int i = 0; i < 9; ++i) f[i] = 1.f;
  if constexpr (MASK) {
    const float* x3 = xin + ((size_t)(b * CHN + 3)) * HW + p;
    const uint8_t* ap = alive_prev + (size_t)b * HW + p;
    const bool rvs[5] = { r > 1, rn, true, rs, r < HH - 2 };
    const bool cvs[5] = { c > 1, cw, true, ce, c < WW - 2 };
    float hm[5][3];
    #pragma unroll
    for (int i = 0; i < 5; ++i) {
      const int off = (i - 2) * WW;
      const bool rv = rvs[i];
      const float a0 = (rv && cvs[0]) ? x3[off - 2] : 0.f;
      const float a1 = (rv && cvs[1]) ? x3[off - 1] : 0.f;
      const float a2 =  rv            ? x3[off]     : 0.f;
      const float a3 = (rv && cvs[3]) ? x3[off + 1] : 0.f;
      const float a4 = (rv && cvs[4]) ? x3[off + 2] : 0.f;
      hm[i][0] = fmaxf(fmaxf(a0, a1), a2);
      hm[i][1] = fmaxf(fmaxf(a1, a2), a3);
      hm[i][2] = fmaxf(fmaxf(a2, a3), a4);
    }
    #pragma unroll
    for (int qr = 0; qr < 3; ++qr)
      #pragma unroll
      for (int qc = 0; qc < 3; ++qc) {
        const float mp = fmaxf(fmaxf(hm[qr][qc], hm[qr + 1][qc]),
                               hm[qr + 2][qc]);
        const bool inb = rvs[qr + 1] && cvs[qc + 1];
        const uint8_t al = inb ? ap[(qr - 1) * WW + (qc - 1)] : (uint8_t)0;
        f[qr * 3 + qc] = (inb && al && (mp > 0.1f)) ? 1.f : 0.f;
      }
  }

  // ---- Conv: wave `sub` does channels 4*sub..4*sub+3; buffer 12 y vals ----
  float n11m[4];
  float yv[12];                       // k-local = cq*3 + d (all static idx)
  #pragma unroll
  for (int cq = 0; cq < 4; ++cq) {
    const int ch = sub * 4 + cq;
    const size_t jb = ((size_t)(b * CHN + ch)) * HW + p;
    const float* xc = xin + jb;
    float n00 = (rn && cw) ? xc[-WW - 1] : 0.f;
    float n01 = rn         ? xc[-WW]     : 0.f;
    float n02 = (rn && ce) ? xc[-WW + 1] : 0.f;
    float n10 = cw         ? xc[-1]      : 0.f;
    float n11 =              xc[0];
    float n12 = ce         ? xc[1]       : 0.f;
    float n20 = (rs && cw) ? xc[WW - 1]  : 0.f;
    float n21 = rs         ? xc[WW]      : 0.f;
    float n22 = (rs && ce) ? xc[WW + 1]  : 0.f;
    if constexpr (MASK) {
      n00 *= f[0]; n01 *= f[1]; n02 *= f[2];
      n10 *= f[3]; n11 *= f[4]; n12 *= f[5];
      n20 *= f[6]; n21 *= f[7]; n22 *= f[8];
      frames_prev[jb] = n11;
    }
    n11m[cq] = n11;
    yv[cq * 3 + 0] = n11;
    yv[cq * 3 + 1] = ((n02 + n22 - n00 - n20) + 2.f * (n12 - n10)) * 0.125f;
    yv[cq * 3 + 2] = ((n20 + n22 - n00 - n02) + 2.f * (n21 - n01)) * 0.125f;
    if (ch == 3) {
      float m = fmaxf(fmaxf(fmaxf(n00, n01), fmaxf(n02, n10)),
                      fmaxf(fmaxf(n11, n12), fmaxf(n20, n21)));
      m = fmaxf(m, n22);
      alive_cur[P + lane] = (m > 0.1f) ? 1 : 0;
    }
  }

  // ---- y 3-term bf16 split -> LDS planes. Thread owns k = sub*12..+12
  //      of row px=lane (contiguous): 3x ushort4 per term. ----
  {
    uint16_t u0[12], u1[12], u2[12];
    #pragma unroll
    for (int i = 0; i < 12; ++i) {
      const float v = yv[i];
      u0[i] = bf16r(v);
      const float r1v = v - bf16f(u0[i]);
      u1[i] = bf16r(r1v);
      u2[i] = bf16r(r1v - bf16f(u1[i]));
    }
    const int rowoff = lane * YS_ROW + sub * 24;      // bytes
    #pragma unroll
    for (int q = 0; q < 3; ++q) {
      *(ushort4*)(smemRaw + 0 * YS_PLANE + rowoff + q * 8) =
          make_ushort4(u0[q*4+0], u0[q*4+1], u0[q*4+2], u0[q*4+3]);
      *(ushort4*)(smemRaw + 1 * YS_PLANE + rowoff + q * 8) =
          make_ushort4(u1[q*4+0], u1[q*4+1], u1[q*4+2], u1[q*4+3]);
      *(ushort4*)(smemRaw + 2 * YS_PLANE + rowoff + q * 8) =
          make_ushort4(u2[q*4+0], u2[q*4+1], u2[q*4+2], u2[q*4+3]);
    }
    // zero-pad k = 48 + sub*4 .. +4 (MFMA kt=1 reads k up to 63)
    const int zoff = lane * YS_ROW + 96 + sub * 8;
    const ushort4 z = make_ushort4(0, 0, 0, 0);
    *(ushort4*)(smemRaw + 0 * YS_PLANE + zoff) = z;
    *(ushort4*)(smemRaw + 1 * YS_PLANE + zoff) = z;
    *(ushort4*)(smemRaw + 2 * YS_PLANE + zoff) = z;
  }

  // ---- Threefry ----
  float keep[4];
  #pragma unroll
  for (int i = 0; i < 4; ++i) {
    const int cc = sub * 4 + i;
    const uint32_t j = (uint32_t)((b * CHN + cc) * HW + p);
    uint32_t o0, o1;
    tf2x32(k0, k1, 0u, j, o0, o1);
    const uint32_t bits = o0 ^ o1;
    keep[i] = ((bits >> 9) > 0x400000u) ? 1.f : 0.f;
  }

  __syncthreads();   // B0: y planes ready

  // ---- GEMM1 via MFMA: D[64px x 32h(sub)] = y[64x48] * w2slice ----
  const int lm = lane & 15;
  const int hq = lane >> 4;                          // 0..3
  f32x4 acc[4][2];
  #pragma unroll
  for (int m = 0; m < 4; ++m)
    #pragma unroll
    for (int t2 = 0; t2 < 2; ++t2) acc[m][t2] = (f32x4){0.f, 0.f, 0.f, 0.f};

  #pragma unroll
  for (int kt = 0; kt < 2; ++kt) {
    bf16x8 bfr[2][3];
    #pragma unroll
    for (int t2 = 0; t2 < 2; ++t2)
      #pragma unroll
      for (int s = 0; s < 3; ++s) {
        const int tn = sub * 2 + t2;
        bfr[t2][s] = *(const bf16x8*)(wfrag +
            (size_t)(((s * 8 + tn) * 2 + kt) * 64 + lane) * 8);
      }
    #pragma unroll
    for (int m = 0; m < 4; ++m) {
      bf16x8 af[3];
      #pragma unroll
      for (int s = 0; s < 3; ++s)
        af[s] = *(const bf16x8*)(smemRaw + s * YS_PLANE +
                                 (m * 16 + lm) * YS_ROW + kt * 64 + hq * 16);
      #pragma unroll
      for (int t2 = 0; t2 < 2; ++t2) {
        // 6 split-terms, ascending magnitude into the same fp32 acc
        acc[m][t2] = __builtin_amdgcn_mfma_f32_16x16x32_bf16(
            af[2], bfr[t2][0], acc[m][t2], 0, 0, 0);
        acc[m][t2] = __builtin_amdgcn_mfma_f32_16x16x32_bf16(
            af[1], bfr[t2][1], acc[m][t2], 0, 0, 0);
        acc[m][t2] = __builtin_amdgcn_mfma_f32_16x16x32_bf16(
            af[0], bfr[t2][2], acc[m][t2], 0, 0, 0);
        acc[m][t2] = __builtin_amdgcn_mfma_f32_16x16x32_bf16(
            af[1], bfr[t2][0], acc[m][t2], 0, 0, 0);
        acc[m][t2] = __builtin_amdgcn_mfma_f32_16x16x32_bf16(
            af[0], bfr[t2][1], acc[m][t2], 0, 0, 0);
        acc[m][t2] = __builtin_amdgcn_mfma_f32_16x16x32_bf16(
            af[0], bfr[t2][0], acc[m][t2], 0, 0, 0);
      }
    }
  }

  __syncthreads();   // B1: all y reads done; region becomes h[128][68]

  // ---- D-frag -> h LDS (verified C/D map: col=lane&15, row=(lane>>4)*4+r).
  //      Wave writes exactly h-cols sub*32..+32 -> wave-local for GEMM2. ----
  #pragma unroll
  for (int m = 0; m < 4; ++m)
    #pragma unroll
    for (int t2 = 0; t2 < 2; ++t2) {
      const int hd = (sub * 2 + t2) * 16 + lm;       // h-dim
      const int px = m * 16 + hq * 4;                // 4 consecutive px
      *(f32x4*)(h_ld + hd * H_STRIDE + px) = acc[m][t2];
    }

  // ---- GEMM2: fp32 VALU; h from own-wave LDS rows; w3 wave-uniform ----
  f32x2 o2[8];
  #pragma unroll
  for (int i = 0; i < 8; ++i) o2[i] = (f32x2){0.f, 0.f};

  const f32x2* w3b2 = (const f32x2*)(w3t + (size_t)sub * 32 * 16);
  #pragma unroll
  for (int hh = 0; hh < 32; ++hh) {
    const float hv = fmaxf(h_ld[(sub * 32 + hh) * H_STRIDE + lane], 0.f);
    const f32x2 hv2 = {hv, hv};
    const f32x2* w3r = w3b2 + hh * 8;
    #pragma unroll
    for (int n = 0; n < 8; ++n)
      o2[n] = __builtin_elementwise_fma(w3r[n], hv2, o2[n]);
  }

  __syncthreads();   // B2: all h reads done; region becomes part[][][]

  #pragma unroll
  for (int cc = 0; cc < CHN; ++cc)
    part[cc][sub][lane] = (cc & 1) ? o2[cc >> 1].y : o2[cc >> 1].x;
  __syncthreads();   // B3

  #pragma unroll
  for (int i = 0; i < 4; ++i) {
    const int cc = sub * 4 + i;
    const float s = (part[cc][0][lane] + part[cc][1][lane]) +
                    (part[cc][2][lane] + part[cc][3][lane]);
    const uint32_t j = (uint32_t)((b * CHN + cc) * HW + p);
    xnew[j] = n11m[i] + keep[i] * s;
  }
}

// Final mask pass (only for frames[23]).
__global__ __launch_bounds__(256) void nca_mask(
    const float* __restrict__ xnew, const uint8_t* __restrict__ alive_pre,
    float* __restrict__ xout)
{
  const int lane = threadIdx.x & 63;
  const int quad = threadIdx.x >> 6;
  const int bid  = blockIdx.x;
  const int vbid = (bid & 7) * 144 + (bid >> 3);
  const int pix  = vbid * 64 + lane;
  const int b = pix / HW;
  const int p = pix - b * HW;
  const int r = p / WW;
  const int c = p - r * WW;
  const bool rn = r > 0, rs = r < HH - 1, cw = c > 0, ce = c < WW - 1;

  const float* x3 = xnew + ((size_t)b * CHN + 3) * HW + p;
  float m = x3[0];
  if (rn) {
    m = fmaxf(m, x3[-WW]);
    if (cw) m = fmaxf(m, x3[-WW - 1]);
    if (ce) m = fmaxf(m, x3[-WW + 1]);
  }
  if (cw) m = fmaxf(m, x3[-1]);
  if (ce) m = fmaxf(m, x3[1]);
  if (rs) {
    m = fmaxf(m, x3[WW]);
    if (cw) m = fmaxf(m, x3[WW - 1]);
    if (ce) m = fmaxf(m, x3[WW + 1]);
  }
  const float f = ((m > 0.1f) && alive_pre[pix]) ? 1.f : 0.f;

  const size_t base = ((size_t)b * CHN + quad * 4) * HW + p;
  #pragma unroll
  for (int i = 0; i < 4; ++i)
    xout[base + (size_t)i * HW] = xnew[base + (size_t)i * HW] * f;
}

extern "C" void kernel_launch(void* const* d_in, const int* in_sizes, int n_in,
                              void* d_out, int out_size, void* d_ws, size_t ws_size,
                              hipStream_t stream) {
  const float* x0 = (const float*)d_in[0];
  const float* w2 = (const float*)d_in[3];  // (128,48)
  const float* w3 = (const float*)d_in[4];  // (16,128)
  float* out = (float*)d_out;               // (24,8,16,96,96)

  // ws: xlast | aliveA | aliveB | w3t | wfrag  (~4.92 MB)
  char* ws = (char*)d_ws;
  float*    xlast  = (float*)ws;                                 // NELEM f32
  uint8_t*  aliveA = (uint8_t*)(ws + (size_t)NELEM * 4);         // NPIX B
  uint8_t*  aliveB = aliveA + NPIX;                              // NPIX B
  float*    w3t    = (float*)(ws + (size_t)NELEM * 4 + 2 * (size_t)NPIX);
  uint16_t* wfrag  = (uint16_t*)((char*)w3t + 8192);             // 24576 u16

  uint32_t keys[T_STEPS][2];
  for (int t = 0; t < T_STEPS; ++t) {
    uint32_t a, b;
    tf2x32(0u, 42u, 0u, (uint32_t)t, a, b);
    keys[t][0] = a; keys[t][1] = b;
  }

  wt_prep<<<104, 256, 0, stream>>>(w2, w3, w3t, wfrag);

  nca_step<false><<<NBLK, 256, 0, stream>>>(
      x0, nullptr, nullptr, out + (size_t)1 * NELEM, aliveA, wfrag, w3t,
      keys[0][0], keys[0][1]);

  for (int t = 1; t < T_STEPS; ++t) {
    const float* xin  = out + (size_t)t * NELEM;
    float* frames_prv = out + (size_t)(t - 1) * NELEM;
    float* xdst = (t < T_STEPS - 1) ? out + (size_t)(t + 1) * NELEM : xlast;
    const uint8_t* aprev = (t & 1) ? aliveA : aliveB;
    uint8_t*       acur  = (t & 1) ? aliveB : aliveA;
    nca_step<true><<<NBLK, 256, 0, stream>>>(
        xin, frames_prv, aprev, xdst, acur, wfrag, w3t,
        keys[t][0], keys[t][1]);
  }

  nca_mask<<<NBLK, 256, 0, stream>>>(
      xlast, (T_STEPS & 1) ? aliveA : aliveB,
      out + (size_t)(T_STEPS - 1) * NELEM);
}